// Round 13
// baseline (204.743 us; speedup 1.0000x reference)
//
#include <hip/hip_runtime.h>
#include <math.h>

typedef unsigned short ushort_t;
typedef __attribute__((ext_vector_type(8))) short short8v;
typedef __attribute__((ext_vector_type(4))) float float4v;

#define BB 2
#define NN 2048
#define HH 16
#define DHH 64
#define DIMM 1024
#define QKV3 3072
#define INNERR 1024
// 0.125 * log2(e): fold attention scale + base-2 exp into Q
#define QSCALE 0.1803368801111244f

__device__ __forceinline__ ushort_t f2bf(float f) {
    unsigned u = __float_as_uint(f);
    u += 0x7fffu + ((u >> 16) & 1u);  // round to nearest even
    return (ushort_t)(u >> 16);
}
__device__ __forceinline__ float bf2f(unsigned h) {
    return __uint_as_float(h << 16);
}
__device__ __forceinline__ unsigned pk_bf16(float a, float b) {
#if __has_builtin(__builtin_amdgcn_cvt_pk_bf16_f32)
    typedef __attribute__((ext_vector_type(2))) __bf16 bf16x2;
    bf16x2 r = __builtin_amdgcn_cvt_pk_bf16_f32(a, b);
    return __builtin_bit_cast(unsigned, r);
#else
    return (unsigned)f2bf(a) | ((unsigned)f2bf(b) << 16);
#endif
}
// bare v_exp_f32 -- OCML exp2f carries denorm/overflow guards we don't need
__device__ __forceinline__ float fast_exp2(float x) {
#if __has_builtin(__builtin_amdgcn_exp2f)
    return __builtin_amdgcn_exp2f(x);
#else
    return exp2f(x);
#endif
}
__device__ __forceinline__ void gl2lds16(const void* g, void* l) {
    __builtin_amdgcn_global_load_lds(
        (const __attribute__((address_space(1))) unsigned int*)g,
        (__attribute__((address_space(3))) unsigned int*)l, 16, 0, 0);
}

// One kernel converts x (4096 blks), w_qkv (3072), w_out (1024) to bf16.
__global__ __launch_bounds__(256) void conv_fused(const float* __restrict__ x,
                                                  const float* __restrict__ wqkv,
                                                  const float* __restrict__ wout,
                                                  ushort_t* __restrict__ xo,
                                                  ushort_t* __restrict__ wqkvo,
                                                  ushort_t* __restrict__ wouto) {
    int blk = blockIdx.x;
    const float* in; ushort_t* out; int i;
    if (blk < 4096)      { in = x;    out = xo;    i = blk * 256 + threadIdx.x; }
    else if (blk < 7168) { in = wqkv; out = wqkvo; i = (blk - 4096) * 256 + threadIdx.x; }
    else                 { in = wout; out = wouto; i = (blk - 7168) * 256 + threadIdx.x; }
    float4 v = ((const float4*)in)[i];
    ushort4 o;
    o.x = f2bf(v.x); o.y = f2bf(v.y); o.z = f2bf(v.z); o.w = f2bf(v.w);
    ((ushort4*)out)[i] = o;
}

// C[m,n] = sum_k A[m,k]*B[n,k] (NT). 128xBN tile, BK=32, 4 waves, 16x16x32 MFMA.
// TRIPLE-buffered staging, prefetch depth 2: iter i prefetches slab i+2 and
// waits vmcnt(2*NCH) (slab i complete, i+1/i+2 still in flight) -> two full
// bodies of load-latency tolerance (R12 was depth 1: both pipes <20% busy).
// Swizzle on (row>>1)&3: rows are 64B (16 banks), so rows 4 apart alias a bank
// slot under the old (row&3) swizzle (4-way, 3.1M conflicts); (row>>1)&3 gives
// 2 rows/slot = 2-way = free.
// ROT (BN=128 only): rotary+QSCALE on q/k col regions; V region (n0>=2048) is
// written transposed+tau-permuted directly to Vt; qkv V third never written.
template <int NOUT, bool BF16OUT, bool BIAS, int BN, bool ROT>
__global__ __launch_bounds__(256) void gemm_bf16(const ushort_t* __restrict__ A,
                                                 const ushort_t* __restrict__ Bm,
                                                 const float* __restrict__ bias,
                                                 const float* __restrict__ rot,
                                                 ushort_t* __restrict__ Vt,
                                                 void* __restrict__ Cout, int K) {
    constexpr int JN = BN / 32;          // B-frags per wave
    constexpr int TOTAL = 512 + BN * 4;  // 16B chunks per K-slab
    constexpr int NCH = TOTAL / 256;     // chunks per thread (4 or 3)
    __shared__ ushort_t As[3][128 * 32];
    __shared__ ushort_t Bs[3][BN * 32];
    const int t = threadIdx.x;
    const int lane = t & 63;
    const int w = t >> 6;
    const int quad = lane >> 4;
    const int l15 = lane & 15;
    const int m0 = blockIdx.y * 128;
    const int n0 = blockIdx.x * BN;
    const int wm = (w >> 1) * 64;
    const int wn = (w & 1) * (BN / 2);

    float4v acc[4][JN];
#pragma unroll
    for (int i = 0; i < 4; ++i)
#pragma unroll
        for (int j = 0; j < JN; ++j) acc[i][j] = (float4v)0.0f;

    // precompute per-thread staging coords (swizzle: (row>>1)&3)
    int srow[NCH], slc[NCH], sdst[NCH];
    bool sisA[NCH];
#pragma unroll
    for (int u = 0; u < NCH; ++u) {
        int c = u * 256 + t;
        if (c < 512) {
            int row = c >> 2;
            sisA[u] = true; srow[u] = row; slc[u] = (c & 3) ^ ((row >> 1) & 3); sdst[u] = c * 8;
        } else {
            int cb = c - 512;
            int row = cb >> 2;
            sisA[u] = false; srow[u] = row; slc[u] = (cb & 3) ^ ((row >> 1) & 3); sdst[u] = cb * 8;
        }
    }
    const int NIT = K >> 5;
    // prologue: stage slabs 0 and 1 into buffers 0 and 1
#pragma unroll
    for (int s = 0; s < 2; ++s)
#pragma unroll
        for (int u = 0; u < NCH; ++u) {
            if (sisA[u]) gl2lds16(&A[(size_t)(m0 + srow[u]) * K + (s << 5) + slc[u] * 8], &As[s][sdst[u]]);
            else         gl2lds16(&Bm[(size_t)(n0 + srow[u]) * K + (s << 5) + slc[u] * 8], &Bs[s][sdst[u]]);
        }
    int cur = 0, nxt2 = 2;
    for (int it = 0; it < NIT; ++it) {
        if (it + 2 < NIT) {
            const int kc = (it + 2) << 5;
#pragma unroll
            for (int u = 0; u < NCH; ++u) {
                if (sisA[u]) gl2lds16(&A[(size_t)(m0 + srow[u]) * K + kc + slc[u] * 8], &As[nxt2][sdst[u]]);
                else         gl2lds16(&Bm[(size_t)(n0 + srow[u]) * K + kc + slc[u] * 8], &Bs[nxt2][sdst[u]]);
            }
            if (NCH == 4) asm volatile("s_waitcnt vmcnt(8)\n\ts_barrier" ::: "memory");
            else          asm volatile("s_waitcnt vmcnt(6)\n\ts_barrier" ::: "memory");
        } else if (it + 1 < NIT) {
            if (NCH == 4) asm volatile("s_waitcnt vmcnt(4)\n\ts_barrier" ::: "memory");
            else          asm volatile("s_waitcnt vmcnt(3)\n\ts_barrier" ::: "memory");
        } else {
            asm volatile("s_waitcnt vmcnt(0)\n\ts_barrier" ::: "memory");
        }
        short8v a[4], b[JN];
#pragma unroll
        for (int i = 0; i < 4; ++i) {
            int row = wm + i * 16 + l15;
            int pc = quad ^ ((row >> 1) & 3);
            a[i] = *(const short8v*)&As[cur][row * 32 + pc * 8];
        }
#pragma unroll
        for (int j = 0; j < JN; ++j) {
            int row = wn + j * 16 + l15;
            int pc = quad ^ ((row >> 1) & 3);
            b[j] = *(const short8v*)&Bs[cur][row * 32 + pc * 8];
        }
#pragma unroll
        for (int i = 0; i < 4; ++i)
#pragma unroll
            for (int j = 0; j < JN; ++j)
                acc[i][j] = __builtin_amdgcn_mfma_f32_16x16x32_bf16(a[i], b[j], acc[i][j], 0, 0, 0);
        // WAR: the next prefetch (slab it+3) overwrites buf cur; all waves'
        // frag reads of buf cur completed above (consumed by MFMAs).
        asm volatile("s_barrier" ::: "memory");
        cur = (cur == 2) ? 0 : cur + 1;
        nxt2 = (nxt2 == 2) ? 0 : nxt2 + 1;
    }
    const int region = ROT ? (n0 >> 10) : 0;  // 0=q, 1=k, 2=v
    if (ROT && region == 2) {
        // V: write transposed + tau-permuted directly to Vt[b,h,dh,n'].
#pragma unroll
        for (int i = 0; i < 4; ++i) {
            int grow = m0 + wm + i * 16 + quad * 4;  // token, ==0 mod 4
            int bb = grow >> 11, nn_ = grow & (NN - 1);
            int tk = nn_ & 63;
            // token bits kb(1)|j2(1)|qd(2)|j1(2) -> stored tp = kb|qd|j2|j1
            int tp = (tk & 32) | ((tk & 12) << 1) | ((tk & 16) >> 2);
            int nstore = (nn_ & ~63) | tp;  // j1=0; +r appends
#pragma unroll
            for (int j = 0; j < JN; ++j) {
                int vcol = n0 + wn + j * 16 + l15 - 2048;
                int hh = vcol >> 6, dh = vcol & 63;
                uint2 st;
                st.x = pk_bf16(acc[i][j][0], acc[i][j][1]);
                st.y = pk_bf16(acc[i][j][2], acc[i][j][3]);
                *(uint2*)&Vt[((size_t)(bb * HH + hh) * DHH + dh) * NN + nstore] = st;
            }
        }
        return;
    }
    if (ROT) {
        float scale = (region == 0) ? QSCALE : 1.0f;
#pragma unroll
        for (int i = 0; i < 4; ++i) {
#pragma unroll
            for (int r = 0; r < 4; ++r) {
                int n = (m0 + wm + i * 16 + quad * 4 + r) & (NN - 1);
#pragma unroll
                for (int jl = 0; jl < 2; ++jl) {
                    int dh = jl * 16 + l15;
                    float plo = rot[n * DHH + dh];
                    float phi = rot[n * DHH + dh + 32];
                    float lo = acc[i][jl][r], hi = acc[i][jl + 2][r];
                    acc[i][jl][r]     = (lo * __cosf(plo) - hi * __sinf(plo)) * scale;
                    acc[i][jl + 2][r] = (hi * __cosf(phi) + lo * __sinf(phi)) * scale;
                }
            }
        }
    }
#pragma unroll
    for (int i = 0; i < 4; ++i) {
        int grow = m0 + wm + i * 16 + quad * 4;
#pragma unroll
        for (int j = 0; j < JN; ++j) {
            int gcol = n0 + wn + j * 16 + l15;
            float bv = BIAS ? bias[gcol] : 0.0f;
#pragma unroll
            for (int r = 0; r < 4; ++r) {
                float v = acc[i][j][r] + bv;
                if (BF16OUT)
                    ((ushort_t*)Cout)[(size_t)(grow + r) * NOUT + gcol] = f2bf(v);
                else
                    ((float*)Cout)[(size_t)(grow + r) * NOUT + gcol] = v;
            }
        }
    }
}

// MFMA flash attention, no-max exp2 softmax, S^T trick (P stays in registers),
// double-buffered K/V staging with raw-asm vmcnt-carrying barriers (R10 form).
// exp2 = bare v_exp_f32. (Unchanged from R12 -- below 56 us, not the leader.)
__global__ __launch_bounds__(256, 4) void flash_mfma(const ushort_t* __restrict__ qkv,
                                                     const ushort_t* __restrict__ Vt,
                                                     ushort_t* __restrict__ po,
                                                     float* __restrict__ lp) {
    __shared__ ushort_t smem[16384];  // 32 KB: Ks0|Ks1|Vts0|Vts1 (4096 each)
    ushort_t* Osc = smem;             // epilogue alias, safe after final barrier
    const int t = threadIdx.x;
    const int lane = t & 63;
    const int w = t >> 6;
    const int quad = lane >> 4;
    const int l15 = lane & 15;
    // blk: low 3 bits = XCD residue; 4 bh per residue class keep K+V in XCD L2
    const int blk = blockIdx.x;  // 1024
    const int slot = blk >> 3;   // 128: ks(1) | qt(4) | bhh(2)
    const int ks = slot & 1;
    const int qt = (slot >> 1) & 15;
    const int bh = (blk & 7) * 4 + (slot >> 5);
    const int b = bh >> 4, h = bh & 15;
    const int n0 = qt * 128;

    // Q as B-operand frags: lane l15 = q-row, k-slots = dh
    short8v bq[2][2];
#pragma unroll
    for (int g = 0; g < 2; ++g) {
        size_t qb = (size_t)(b * NN + n0 + w * 32 + g * 16 + l15) * QKV3 + h * DHH + quad * 8;
        bq[g][0] = *(const short8v*)&qkv[qb];
        bq[g][1] = *(const short8v*)&qkv[qb + 32];
    }
    float4v o_acc[2][4];
    float4v l_acc[2];
#pragma unroll
    for (int g = 0; g < 2; ++g) {
        l_acc[g] = (float4v)0.0f;
#pragma unroll
        for (int nb = 0; nb < 4; ++nb) o_acc[g][nb] = (float4v)0.0f;
    }
    const short one_bf = (short)0x3F80;
    short8v ones8 = {one_bf, one_bf, one_bf, one_bf, one_bf, one_bf, one_bf, one_bf};

    // staging: K 512 chunks + V 512 chunks over 256 threads (2 each)
    const int s0 = t, s1 = 256 + t;
    const int r0 = s0 >> 3, lc0 = (s0 & 7) ^ (r0 & 7);
    const int r1 = s1 >> 3, lc1 = (s1 & 7) ^ (r1 & 7);
    const int koff0 = r0 * QKV3 + lc0 * 8, koff1 = r1 * QKV3 + lc1 * 8;
    const int voff0 = r0 * NN + lc0 * 8,   voff1 = r1 * NN + lc1 * 8;
    const ushort_t* kp = qkv + (size_t)b * NN * QKV3 + INNERR + h * DHH + (size_t)ks * 1024 * QKV3;
    const ushort_t* vp = Vt + (size_t)(b * HH + h) * DHH * NN + ks * 1024;

    // prologue: stage tile 0 into buffer 0
    {
        gl2lds16(kp + koff0, smem + 0 * 4096 + s0 * 8);
        gl2lds16(kp + koff1, smem + 0 * 4096 + s1 * 8);
        gl2lds16(vp + voff0, smem + 2 * 4096 + s0 * 8);
        gl2lds16(vp + voff1, smem + 2 * 4096 + s1 * 8);
    }
    for (int jt = 0; jt < 16; ++jt) {
        const int cur = jt & 1;
        if (jt < 15) {
            // prefetch tile jt+1 into the alternate buffer (stays in flight
            // across the barrier: we only wait for the 4 OLDER loads)
            kp += 64 * QKV3;
            vp += 64;
            const int nxt = cur ^ 1;
            gl2lds16(kp + koff0, smem + nxt * 4096 + s0 * 8);
            gl2lds16(kp + koff1, smem + nxt * 4096 + s1 * 8);
            gl2lds16(vp + voff0, smem + (2 + nxt) * 4096 + s0 * 8);
            gl2lds16(vp + voff1, smem + (2 + nxt) * 4096 + s1 * 8);
            asm volatile("s_waitcnt vmcnt(4)\n\ts_barrier" ::: "memory");
        } else {
            asm volatile("s_waitcnt vmcnt(0)\n\ts_barrier" ::: "memory");
        }
        const ushort_t* Ksc = smem + cur * 4096;
        const ushort_t* Vtc = smem + (2 + cur) * 4096;
        // S^T = K Q^T : lane l15 = q-row, rows (quad*4+r | nb*16) = key position
        float4v s_acc[2][4];
#pragma unroll
        for (int g = 0; g < 2; ++g)
#pragma unroll
            for (int nb = 0; nb < 4; ++nb) s_acc[g][nb] = (float4v)0.0f;
#pragma unroll
        for (int kb = 0; kb < 2; ++kb)
#pragma unroll
            for (int nb = 0; nb < 4; ++nb) {
                int row = nb * 16 + l15;
                int pc = (kb * 4 + quad) ^ (row & 7);
                short8v ak = *(const short8v*)&Ksc[row * 64 + pc * 8];
                s_acc[0][nb] = __builtin_amdgcn_mfma_f32_16x16x32_bf16(ak, bq[0][kb], s_acc[0][nb], 0, 0, 0);
                s_acc[1][nb] = __builtin_amdgcn_mfma_f32_16x16x32_bf16(ak, bq[1][kb], s_acc[1][nb], 0, 0, 0);
            }
        // per-g: exp2+pack then that g's MFMAs (lets g=0 MFMAs hide g=1 exp2)
#pragma unroll
        for (int g = 0; g < 2; ++g) {
            float p[4][4];
#pragma unroll
            for (int nb = 0; nb < 4; ++nb)
#pragma unroll
                for (int r = 0; r < 4; ++r) p[nb][r] = fast_exp2(s_acc[g][nb][r]);
            uint4 u0, u1;
            u0.x = pk_bf16(p[0][0], p[0][1]); u0.y = pk_bf16(p[0][2], p[0][3]);
            u0.z = pk_bf16(p[1][0], p[1][1]); u0.w = pk_bf16(p[1][2], p[1][3]);
            u1.x = pk_bf16(p[2][0], p[2][1]); u1.y = pk_bf16(p[2][2], p[2][3]);
            u1.z = pk_bf16(p[3][0], p[3][1]); u1.w = pk_bf16(p[3][2], p[3][3]);
            short8v ap0 = __builtin_bit_cast(short8v, u0);
            short8v ap1 = __builtin_bit_cast(short8v, u1);
            l_acc[g] = __builtin_amdgcn_mfma_f32_16x16x32_bf16(ap0, ones8, l_acc[g], 0, 0, 0);
            l_acc[g] = __builtin_amdgcn_mfma_f32_16x16x32_bf16(ap1, ones8, l_acc[g], 0, 0, 0);
#pragma unroll
            for (int nb = 0; nb < 4; ++nb) {
                int row = nb * 16 + l15;
                int pc0 = quad ^ (row & 7);
                int pc1 = (4 + quad) ^ (row & 7);
                short8v bv0 = *(const short8v*)&Vtc[row * 64 + pc0 * 8];
                short8v bv1 = *(const short8v*)&Vtc[row * 64 + pc1 * 8];
                o_acc[g][nb] = __builtin_amdgcn_mfma_f32_16x16x32_bf16(ap0, bv0, o_acc[g][nb], 0, 0, 0);
                o_acc[g][nb] = __builtin_amdgcn_mfma_f32_16x16x32_bf16(ap1, bv1, o_acc[g][nb], 0, 0, 0);
            }
        }
        // WAR guard: next iteration overwrites buf cur
        asm volatile("s_barrier" ::: "memory");
    }
    // l: C-layout of ones-MFMA -> row (q-row) = quad*4+r, all cols identical
#pragma unroll
    for (int g = 0; g < 2; ++g) {
        if (l15 == 0)
            *(float4*)&lp[(size_t)(ks * 32 + bh) * NN + n0 + w * 32 + g * 16 + quad * 4] =
                *(float4*)&l_acc[g];
    }
    // O epilogue: C-layout (lane=dh-within-nb, reg=q-row) -> wave-private LDS
    // transpose -> coalesced 16B stores
    ushort_t* osc = Osc + w * (32 * 68);
#pragma unroll
    for (int g = 0; g < 2; ++g)
#pragma unroll
        for (int nb = 0; nb < 4; ++nb)
#pragma unroll
            for (int r = 0; r < 4; ++r)
                osc[(g * 16 + quad * 4 + r) * 68 + nb * 16 + l15] = f2bf(o_acc[g][nb][r]);
    __builtin_amdgcn_s_waitcnt(0);  // lgkmcnt(0): wave-private LDS ordering
    {
        int rr = lane >> 1, c0 = (lane & 1) * 32;
        size_t prow = ((size_t)(ks * 32 + bh) * NN + n0 + w * 32 + rr) * DHH + c0;
#pragma unroll
        for (int u = 0; u < 4; ++u) {
            uint4 v = *(const uint4*)&osc[rr * 68 + c0 + u * 8];
            *(uint4*)&po[prow + u * 8] = v;
        }
    }
}

// attn[b,n,h*64+dh] = (po0 + po1) / (l0 + l1)
__global__ __launch_bounds__(256) void reduce_o(const ushort_t* __restrict__ po,
                                                const float* __restrict__ lp,
                                                ushort_t* __restrict__ attn) {
    int tg = blockIdx.x * 256 + threadIdx.x;  // 1M threads, 4 dh each
    int bh = tg >> 15;
    int rem = tg & 32767;
    int n = rem >> 4;
    int dh0 = (rem & 15) * 4;
    size_t p0 = ((size_t)bh * NN + n) * DHH + dh0;
    size_t p1 = p0 + (size_t)32 * NN * DHH;
    uint2 a = *(const uint2*)&po[p0];
    uint2 c = *(const uint2*)&po[p1];
    float inv = 1.0f / (lp[(size_t)bh * NN + n] + lp[(size_t)(32 + bh) * NN + n]);
    float o0 = (bf2f(a.x & 0xffff) + bf2f(c.x & 0xffff)) * inv;
    float o1 = (bf2f(a.x >> 16)    + bf2f(c.x >> 16))    * inv;
    float o2 = (bf2f(a.y & 0xffff) + bf2f(c.y & 0xffff)) * inv;
    float o3 = (bf2f(a.y >> 16)    + bf2f(c.y >> 16))    * inv;
    int b = bh >> 4, h = bh & 15;
    uint2 st;
    st.x = pk_bf16(o0, o1);
    st.y = pk_bf16(o2, o3);
    *(uint2*)&attn[((size_t)(b * NN + n)) * INNERR + h * DHH + dh0] = st;
}

extern "C" void kernel_launch(void* const* d_in, const int* in_sizes, int n_in,
                              void* d_out, int out_size, void* d_ws, size_t ws_size,
                              hipStream_t stream) {
    const float* x = (const float*)d_in[0];       // [2,2048,1024]
    const float* rot = (const float*)d_in[1];     // [2048,64]
    const float* w_qkv = (const float*)d_in[2];   // [3072,1024]
    const float* w_out = (const float*)d_in[3];   // [1024,1024]
    const float* b_out = (const float*)d_in[4];   // [1024]
    float* y = (float*)d_out;                     // [2,2048,1024] fp32

    char* ws = (char*)d_ws;
    ushort_t* qkv_bf  = (ushort_t*)(ws);               // 25,165,824 B [4096,3072] bf16 (V third unused)
    ushort_t* vt_bf   = (ushort_t*)(ws + 25165824);    //  8,388,608 B [b,h,64,2048] (tau-permuted)
    ushort_t* wout_bf = (ushort_t*)(ws + 33554432);    //  2,097,152 B
    ushort_t* wqkv_bf = (ushort_t*)(ws + 35651584);    //  6,291,456 B (dead after GEMM1)
    float*    lp      = (float*)(ws + 35651584);       //    524,288 B (aliases wqkv_bf)
    ushort_t* x_bf    = (ushort_t*)(ws + 41943040);    //  8,388,608 B (dead after GEMM1)
    ushort_t* attn_bf = x_bf;                          //             (aliases x_bf)
    ushort_t* po      = (ushort_t*)(ws + 50331648);    // 16,777,216 B -> 64 MiB total

    conv_fused<<<8192, 256, 0, stream>>>(x, w_qkv, w_out, x_bf, wqkv_bf, wout_bf);
    // qkv = x @ w_qkv^T -> bf16 (q/k rotary-fused); V cols -> Vt directly
    gemm_bf16<QKV3, true, false, 128, true><<<dim3(24, 32), 256, 0, stream>>>(
        x_bf, wqkv_bf, nullptr, rot, vt_bf, qkv_bf, DIMM);
    // flash attention, 2-way K-split -> partial O (bf16) + l (fp32)
    flash_mfma<<<1024, 256, 0, stream>>>(qkv_bf, vt_bf, po, lp);
    // combine splits -> attn bf16 [4096,1024]
    reduce_o<<<4096, 256, 0, stream>>>(po, lp, attn_bf);
    // y = attn @ w_out^T + b_out -> fp32
    gemm_bf16<INNERR, false, true, 64, false><<<dim3(16, 32), 256, 0, stream>>>(
        attn_bf, wout_bf, b_out, nullptr, nullptr, y, INNERR);
}

// Round 14
// 201.261 us; speedup vs baseline: 1.0173x; 1.0173x over previous
//
#include <hip/hip_runtime.h>
#include <math.h>

typedef unsigned short ushort_t;
typedef __attribute__((ext_vector_type(8))) short short8v;
typedef __attribute__((ext_vector_type(4))) float float4v;

#define BB 2
#define NN 2048
#define HH 16
#define DHH 64
#define DIMM 1024
#define QKV3 3072
#define INNERR 1024
// 0.125 * log2(e): fold attention scale + base-2 exp into Q
#define QSCALE 0.1803368801111244f

__device__ __forceinline__ ushort_t f2bf(float f) {
    unsigned u = __float_as_uint(f);
    u += 0x7fffu + ((u >> 16) & 1u);  // round to nearest even
    return (ushort_t)(u >> 16);
}
__device__ __forceinline__ float bf2f(unsigned h) {
    return __uint_as_float(h << 16);
}
__device__ __forceinline__ unsigned pk_bf16(float a, float b) {
#if __has_builtin(__builtin_amdgcn_cvt_pk_bf16_f32)
    typedef __attribute__((ext_vector_type(2))) __bf16 bf16x2;
    bf16x2 r = __builtin_amdgcn_cvt_pk_bf16_f32(a, b);
    return __builtin_bit_cast(unsigned, r);
#else
    return (unsigned)f2bf(a) | ((unsigned)f2bf(b) << 16);
#endif
}
// bare v_exp_f32 -- OCML exp2f carries denorm/overflow guards we don't need
__device__ __forceinline__ float fast_exp2(float x) {
#if __has_builtin(__builtin_amdgcn_exp2f)
    return __builtin_amdgcn_exp2f(x);
#else
    return exp2f(x);
#endif
}
__device__ __forceinline__ void gl2lds16(const void* g, void* l) {
    __builtin_amdgcn_global_load_lds(
        (const __attribute__((address_space(1))) unsigned int*)g,
        (__attribute__((address_space(3))) unsigned int*)l, 16, 0, 0);
}

// One kernel converts x (4096 blks), w_qkv (3072), w_out (1024) to bf16.
__global__ __launch_bounds__(256) void conv_fused(const float* __restrict__ x,
                                                  const float* __restrict__ wqkv,
                                                  const float* __restrict__ wout,
                                                  ushort_t* __restrict__ xo,
                                                  ushort_t* __restrict__ wqkvo,
                                                  ushort_t* __restrict__ wouto) {
    int blk = blockIdx.x;
    const float* in; ushort_t* out; int i;
    if (blk < 4096)      { in = x;    out = xo;    i = blk * 256 + threadIdx.x; }
    else if (blk < 7168) { in = wqkv; out = wqkvo; i = (blk - 4096) * 256 + threadIdx.x; }
    else                 { in = wout; out = wouto; i = (blk - 7168) * 256 + threadIdx.x; }
    float4 v = ((const float4*)in)[i];
    ushort4 o;
    o.x = f2bf(v.x); o.y = f2bf(v.y); o.z = f2bf(v.z); o.w = f2bf(v.w);
    ((ushort4*)out)[i] = o;
}

// C[m,n] = sum_k A[m,k]*B[n,k] (NT). 128x64 tile, BK=32, 16x16x32 MFMA.
// Wave layout: 4 waves x 32-row slices, each spanning the full 64 cols
// (IM=2 A-frags, JN=4 B-frags, 8 MFMA/wave-iter). 64-wide tiles double the
// grid vs BN=128 (GEMM1: 1536 blocks = 6/CU; R12/13 showed 3/CU left every
// pipe <20% busy -- occupancy-bound). Dbuf + vmcnt-carrying barriers (R10),
// conflict-free (row>>1)&3 swizzle (R13).
// ROT: rotary+QSCALE on q/k col regions (wave spans dh and dh+32 in-wave);
// V region (n0>=2048) written transposed+tau-permuted directly to Vt.
template <int NOUT, bool BF16OUT, bool BIAS, bool ROT>
__global__ __launch_bounds__(256, 6) void gemm_bf16(const ushort_t* __restrict__ A,
                                                    const ushort_t* __restrict__ Bm,
                                                    const float* __restrict__ bias,
                                                    const float* __restrict__ rot,
                                                    ushort_t* __restrict__ Vt,
                                                    void* __restrict__ Cout, int K) {
    constexpr int NCH = 3;  // (512 A + 256 B chunks) / 256 threads
    __shared__ ushort_t As[2][128 * 32];
    __shared__ ushort_t Bs[2][64 * 32];
    const int t = threadIdx.x;
    const int lane = t & 63;
    const int w = t >> 6;
    const int quad = lane >> 4;
    const int l15 = lane & 15;
    const int m0 = blockIdx.y * 128;
    const int n0 = blockIdx.x * 64;
    const int wm = w * 32;

    float4v acc[2][4];
#pragma unroll
    for (int i = 0; i < 2; ++i)
#pragma unroll
        for (int j = 0; j < 4; ++j) acc[i][j] = (float4v)0.0f;

    // per-thread staging coords (swizzle (row>>1)&3; conflict-free)
    int srow[NCH], slc[NCH], sdst[NCH];
    bool sisA[NCH];
#pragma unroll
    for (int u = 0; u < NCH; ++u) {
        int c = u * 256 + t;
        if (c < 512) {
            int row = c >> 2;
            sisA[u] = true; srow[u] = row; slc[u] = (c & 3) ^ ((row >> 1) & 3); sdst[u] = c * 8;
        } else {
            int cb = c - 512;
            int row = cb >> 2;
            sisA[u] = false; srow[u] = row; slc[u] = (cb & 3) ^ ((row >> 1) & 3); sdst[u] = cb * 8;
        }
    }
    // prologue: stage slab 0 into buffer 0
#pragma unroll
    for (int u = 0; u < NCH; ++u) {
        if (sisA[u]) gl2lds16(&A[(size_t)(m0 + srow[u]) * K + slc[u] * 8], &As[0][sdst[u]]);
        else         gl2lds16(&Bm[(size_t)(n0 + srow[u]) * K + slc[u] * 8], &Bs[0][sdst[u]]);
    }
    const int NIT = K >> 5;
    for (int it = 0; it < NIT; ++it) {
        const int cur = it & 1;
        if (it + 1 < NIT) {
            const int nxt = cur ^ 1;
            const int kc = (it + 1) << 5;
#pragma unroll
            for (int u = 0; u < NCH; ++u) {
                if (sisA[u]) gl2lds16(&A[(size_t)(m0 + srow[u]) * K + kc + slc[u] * 8], &As[nxt][sdst[u]]);
                else         gl2lds16(&Bm[(size_t)(n0 + srow[u]) * K + kc + slc[u] * 8], &Bs[nxt][sdst[u]]);
            }
            asm volatile("s_waitcnt vmcnt(3)\n\ts_barrier" ::: "memory");
        } else {
            asm volatile("s_waitcnt vmcnt(0)\n\ts_barrier" ::: "memory");
        }
        short8v a[2], b[4];
#pragma unroll
        for (int i = 0; i < 2; ++i) {
            int row = wm + i * 16 + l15;
            int pc = quad ^ ((row >> 1) & 3);
            a[i] = *(const short8v*)&As[cur][row * 32 + pc * 8];
        }
#pragma unroll
        for (int j = 0; j < 4; ++j) {
            int row = j * 16 + l15;
            int pc = quad ^ ((row >> 1) & 3);
            b[j] = *(const short8v*)&Bs[cur][row * 32 + pc * 8];
        }
#pragma unroll
        for (int i = 0; i < 2; ++i)
#pragma unroll
            for (int j = 0; j < 4; ++j)
                acc[i][j] = __builtin_amdgcn_mfma_f32_16x16x32_bf16(a[i], b[j], acc[i][j], 0, 0, 0);
        // WAR: next iteration's prefetch overwrites buf cur
        asm volatile("s_barrier" ::: "memory");
    }
    const int region = ROT ? (n0 >> 10) : 0;  // 0=q, 1=k, 2=v
    if (ROT && region == 2) {
        // V: write transposed + tau-permuted directly to Vt[b,h,dh,n'].
#pragma unroll
        for (int i = 0; i < 2; ++i) {
            int grow = m0 + wm + i * 16 + quad * 4;  // token, ==0 mod 4
            int bb = grow >> 11, nn_ = grow & (NN - 1);
            int tk = nn_ & 63;
            // token bits kb(1)|j2(1)|qd(2)|j1(2) -> stored tp = kb|qd|j2|j1
            int tp = (tk & 32) | ((tk & 12) << 1) | ((tk & 16) >> 2);
            int nstore = (nn_ & ~63) | tp;  // j1=0; +r appends
#pragma unroll
            for (int j = 0; j < 4; ++j) {
                int vcol = n0 + j * 16 + l15 - 2048;
                int hh = vcol >> 6, dh = vcol & 63;
                uint2 st;
                st.x = pk_bf16(acc[i][j][0], acc[i][j][1]);
                st.y = pk_bf16(acc[i][j][2], acc[i][j][3]);
                *(uint2*)&Vt[((size_t)(bb * HH + hh) * DHH + dh) * NN + nstore] = st;
            }
        }
        return;
    }
    if (ROT) {
        float scale = (region == 0) ? QSCALE : 1.0f;
#pragma unroll
        for (int i = 0; i < 2; ++i) {
#pragma unroll
            for (int r = 0; r < 4; ++r) {
                int n = (m0 + wm + i * 16 + quad * 4 + r) & (NN - 1);
#pragma unroll
                for (int jl = 0; jl < 2; ++jl) {
                    int dh = jl * 16 + l15;
                    float plo = rot[n * DHH + dh];
                    float phi = rot[n * DHH + dh + 32];
                    float lo = acc[i][jl][r], hi = acc[i][jl + 2][r];
                    acc[i][jl][r]     = (lo * __cosf(plo) - hi * __sinf(plo)) * scale;
                    acc[i][jl + 2][r] = (hi * __cosf(phi) + lo * __sinf(phi)) * scale;
                }
            }
        }
    }
#pragma unroll
    for (int i = 0; i < 2; ++i) {
        int grow = m0 + wm + i * 16 + quad * 4;
#pragma unroll
        for (int j = 0; j < 4; ++j) {
            int gcol = n0 + j * 16 + l15;
            float bv = BIAS ? bias[gcol] : 0.0f;
#pragma unroll
            for (int r = 0; r < 4; ++r) {
                float v = acc[i][j][r] + bv;
                if (BF16OUT)
                    ((ushort_t*)Cout)[(size_t)(grow + r) * NOUT + gcol] = f2bf(v);
                else
                    ((float*)Cout)[(size_t)(grow + r) * NOUT + gcol] = v;
            }
        }
    }
}

// MFMA flash attention, no-max exp2 softmax, S^T trick (P stays in registers),
// double-buffered K/V staging with raw-asm vmcnt-carrying barriers (R10 form).
// exp2 = bare v_exp_f32. (Unchanged -- not the current leader.)
__global__ __launch_bounds__(256, 4) void flash_mfma(const ushort_t* __restrict__ qkv,
                                                     const ushort_t* __restrict__ Vt,
                                                     ushort_t* __restrict__ po,
                                                     float* __restrict__ lp) {
    __shared__ ushort_t smem[16384];  // 32 KB: Ks0|Ks1|Vts0|Vts1 (4096 each)
    ushort_t* Osc = smem;             // epilogue alias, safe after final barrier
    const int t = threadIdx.x;
    const int lane = t & 63;
    const int w = t >> 6;
    const int quad = lane >> 4;
    const int l15 = lane & 15;
    // blk: low 3 bits = XCD residue; 4 bh per residue class keep K+V in XCD L2
    const int blk = blockIdx.x;  // 1024
    const int slot = blk >> 3;   // 128: ks(1) | qt(4) | bhh(2)
    const int ks = slot & 1;
    const int qt = (slot >> 1) & 15;
    const int bh = (blk & 7) * 4 + (slot >> 5);
    const int b = bh >> 4, h = bh & 15;
    const int n0 = qt * 128;

    // Q as B-operand frags: lane l15 = q-row, k-slots = dh
    short8v bq[2][2];
#pragma unroll
    for (int g = 0; g < 2; ++g) {
        size_t qb = (size_t)(b * NN + n0 + w * 32 + g * 16 + l15) * QKV3 + h * DHH + quad * 8;
        bq[g][0] = *(const short8v*)&qkv[qb];
        bq[g][1] = *(const short8v*)&qkv[qb + 32];
    }
    float4v o_acc[2][4];
    float4v l_acc[2];
#pragma unroll
    for (int g = 0; g < 2; ++g) {
        l_acc[g] = (float4v)0.0f;
#pragma unroll
        for (int nb = 0; nb < 4; ++nb) o_acc[g][nb] = (float4v)0.0f;
    }
    const short one_bf = (short)0x3F80;
    short8v ones8 = {one_bf, one_bf, one_bf, one_bf, one_bf, one_bf, one_bf, one_bf};

    // staging: K 512 chunks + V 512 chunks over 256 threads (2 each)
    const int s0 = t, s1 = 256 + t;
    const int r0 = s0 >> 3, lc0 = (s0 & 7) ^ (r0 & 7);
    const int r1 = s1 >> 3, lc1 = (s1 & 7) ^ (r1 & 7);
    const int koff0 = r0 * QKV3 + lc0 * 8, koff1 = r1 * QKV3 + lc1 * 8;
    const int voff0 = r0 * NN + lc0 * 8,   voff1 = r1 * NN + lc1 * 8;
    const ushort_t* kp = qkv + (size_t)b * NN * QKV3 + INNERR + h * DHH + (size_t)ks * 1024 * QKV3;
    const ushort_t* vp = Vt + (size_t)(b * HH + h) * DHH * NN + ks * 1024;

    // prologue: stage tile 0 into buffer 0
    {
        gl2lds16(kp + koff0, smem + 0 * 4096 + s0 * 8);
        gl2lds16(kp + koff1, smem + 0 * 4096 + s1 * 8);
        gl2lds16(vp + voff0, smem + 2 * 4096 + s0 * 8);
        gl2lds16(vp + voff1, smem + 2 * 4096 + s1 * 8);
    }
    for (int jt = 0; jt < 16; ++jt) {
        const int cur = jt & 1;
        if (jt < 15) {
            kp += 64 * QKV3;
            vp += 64;
            const int nxt = cur ^ 1;
            gl2lds16(kp + koff0, smem + nxt * 4096 + s0 * 8);
            gl2lds16(kp + koff1, smem + nxt * 4096 + s1 * 8);
            gl2lds16(vp + voff0, smem + (2 + nxt) * 4096 + s0 * 8);
            gl2lds16(vp + voff1, smem + (2 + nxt) * 4096 + s1 * 8);
            asm volatile("s_waitcnt vmcnt(4)\n\ts_barrier" ::: "memory");
        } else {
            asm volatile("s_waitcnt vmcnt(0)\n\ts_barrier" ::: "memory");
        }
        const ushort_t* Ksc = smem + cur * 4096;
        const ushort_t* Vtc = smem + (2 + cur) * 4096;
        // S^T = K Q^T : lane l15 = q-row, rows (quad*4+r | nb*16) = key position
        float4v s_acc[2][4];
#pragma unroll
        for (int g = 0; g < 2; ++g)
#pragma unroll
            for (int nb = 0; nb < 4; ++nb) s_acc[g][nb] = (float4v)0.0f;
#pragma unroll
        for (int kb = 0; kb < 2; ++kb)
#pragma unroll
            for (int nb = 0; nb < 4; ++nb) {
                int row = nb * 16 + l15;
                int pc = (kb * 4 + quad) ^ (row & 7);
                short8v ak = *(const short8v*)&Ksc[row * 64 + pc * 8];
                s_acc[0][nb] = __builtin_amdgcn_mfma_f32_16x16x32_bf16(ak, bq[0][kb], s_acc[0][nb], 0, 0, 0);
                s_acc[1][nb] = __builtin_amdgcn_mfma_f32_16x16x32_bf16(ak, bq[1][kb], s_acc[1][nb], 0, 0, 0);
            }
        // per-g: exp2+pack then that g's MFMAs (lets g=0 MFMAs hide g=1 exp2)
#pragma unroll
        for (int g = 0; g < 2; ++g) {
            float p[4][4];
#pragma unroll
            for (int nb = 0; nb < 4; ++nb)
#pragma unroll
                for (int r = 0; r < 4; ++r) p[nb][r] = fast_exp2(s_acc[g][nb][r]);
            uint4 u0, u1;
            u0.x = pk_bf16(p[0][0], p[0][1]); u0.y = pk_bf16(p[0][2], p[0][3]);
            u0.z = pk_bf16(p[1][0], p[1][1]); u0.w = pk_bf16(p[1][2], p[1][3]);
            u1.x = pk_bf16(p[2][0], p[2][1]); u1.y = pk_bf16(p[2][2], p[2][3]);
            u1.z = pk_bf16(p[3][0], p[3][1]); u1.w = pk_bf16(p[3][2], p[3][3]);
            short8v ap0 = __builtin_bit_cast(short8v, u0);
            short8v ap1 = __builtin_bit_cast(short8v, u1);
            l_acc[g] = __builtin_amdgcn_mfma_f32_16x16x32_bf16(ap0, ones8, l_acc[g], 0, 0, 0);
            l_acc[g] = __builtin_amdgcn_mfma_f32_16x16x32_bf16(ap1, ones8, l_acc[g], 0, 0, 0);
#pragma unroll
            for (int nb = 0; nb < 4; ++nb) {
                int row = nb * 16 + l15;
                int pc0 = quad ^ (row & 7);
                int pc1 = (4 + quad) ^ (row & 7);
                short8v bv0 = *(const short8v*)&Vtc[row * 64 + pc0 * 8];
                short8v bv1 = *(const short8v*)&Vtc[row * 64 + pc1 * 8];
                o_acc[g][nb] = __builtin_amdgcn_mfma_f32_16x16x32_bf16(ap0, bv0, o_acc[g][nb], 0, 0, 0);
                o_acc[g][nb] = __builtin_amdgcn_mfma_f32_16x16x32_bf16(ap1, bv1, o_acc[g][nb], 0, 0, 0);
            }
        }
        // WAR guard: next iteration overwrites buf cur
        asm volatile("s_barrier" ::: "memory");
    }
    // l: C-layout of ones-MFMA -> row (q-row) = quad*4+r, all cols identical
#pragma unroll
    for (int g = 0; g < 2; ++g) {
        if (l15 == 0)
            *(float4*)&lp[(size_t)(ks * 32 + bh) * NN + n0 + w * 32 + g * 16 + quad * 4] =
                *(float4*)&l_acc[g];
    }
    // O epilogue: C-layout (lane=dh-within-nb, reg=q-row) -> wave-private LDS
    // transpose -> coalesced 16B stores
    ushort_t* osc = Osc + w * (32 * 68);
#pragma unroll
    for (int g = 0; g < 2; ++g)
#pragma unroll
        for (int nb = 0; nb < 4; ++nb)
#pragma unroll
            for (int r = 0; r < 4; ++r)
                osc[(g * 16 + quad * 4 + r) * 68 + nb * 16 + l15] = f2bf(o_acc[g][nb][r]);
    __builtin_amdgcn_s_waitcnt(0);  // lgkmcnt(0): wave-private LDS ordering
    {
        int rr = lane >> 1, c0 = (lane & 1) * 32;
        size_t prow = ((size_t)(ks * 32 + bh) * NN + n0 + w * 32 + rr) * DHH + c0;
#pragma unroll
        for (int u = 0; u < 4; ++u) {
            uint4 v = *(const uint4*)&osc[rr * 68 + c0 + u * 8];
            *(uint4*)&po[prow + u * 8] = v;
        }
    }
}

// attn[b,n,h*64+dh] = (po0 + po1) / (l0 + l1)
__global__ __launch_bounds__(256) void reduce_o(const ushort_t* __restrict__ po,
                                                const float* __restrict__ lp,
                                                ushort_t* __restrict__ attn) {
    int tg = blockIdx.x * 256 + threadIdx.x;  // 1M threads, 4 dh each
    int bh = tg >> 15;
    int rem = tg & 32767;
    int n = rem >> 4;
    int dh0 = (rem & 15) * 4;
    size_t p0 = ((size_t)bh * NN + n) * DHH + dh0;
    size_t p1 = p0 + (size_t)32 * NN * DHH;
    uint2 a = *(const uint2*)&po[p0];
    uint2 c = *(const uint2*)&po[p1];
    float inv = 1.0f / (lp[(size_t)bh * NN + n] + lp[(size_t)(32 + bh) * NN + n]);
    float o0 = (bf2f(a.x & 0xffff) + bf2f(c.x & 0xffff)) * inv;
    float o1 = (bf2f(a.x >> 16)    + bf2f(c.x >> 16))    * inv;
    float o2 = (bf2f(a.y & 0xffff) + bf2f(c.y & 0xffff)) * inv;
    float o3 = (bf2f(a.y >> 16)    + bf2f(c.y >> 16))    * inv;
    int b = bh >> 4, h = bh & 15;
    uint2 st;
    st.x = pk_bf16(o0, o1);
    st.y = pk_bf16(o2, o3);
    *(uint2*)&attn[((size_t)(b * NN + n)) * INNERR + h * DHH + dh0] = st;
}

extern "C" void kernel_launch(void* const* d_in, const int* in_sizes, int n_in,
                              void* d_out, int out_size, void* d_ws, size_t ws_size,
                              hipStream_t stream) {
    const float* x = (const float*)d_in[0];       // [2,2048,1024]
    const float* rot = (const float*)d_in[1];     // [2048,64]
    const float* w_qkv = (const float*)d_in[2];   // [3072,1024]
    const float* w_out = (const float*)d_in[3];   // [1024,1024]
    const float* b_out = (const float*)d_in[4];   // [1024]
    float* y = (float*)d_out;                     // [2,2048,1024] fp32

    char* ws = (char*)d_ws;
    ushort_t* qkv_bf  = (ushort_t*)(ws);               // 25,165,824 B [4096,3072] bf16 (V third unused)
    ushort_t* vt_bf   = (ushort_t*)(ws + 25165824);    //  8,388,608 B [b,h,64,2048] (tau-permuted)
    ushort_t* wout_bf = (ushort_t*)(ws + 33554432);    //  2,097,152 B
    ushort_t* wqkv_bf = (ushort_t*)(ws + 35651584);    //  6,291,456 B (dead after GEMM1)
    float*    lp      = (float*)(ws + 35651584);       //    524,288 B (aliases wqkv_bf)
    ushort_t* x_bf    = (ushort_t*)(ws + 41943040);    //  8,388,608 B (dead after GEMM1)
    ushort_t* attn_bf = x_bf;                          //             (aliases x_bf)
    ushort_t* po      = (ushort_t*)(ws + 50331648);    // 16,777,216 B -> 64 MiB total

    conv_fused<<<8192, 256, 0, stream>>>(x, w_qkv, w_out, x_bf, wqkv_bf, wout_bf);
    // qkv = x @ w_qkv^T -> bf16 (q/k rotary-fused); V cols -> Vt directly
    gemm_bf16<QKV3, true, false, true><<<dim3(48, 32), 256, 0, stream>>>(
        x_bf, wqkv_bf, nullptr, rot, vt_bf, qkv_bf, DIMM);
    // flash attention, 2-way K-split -> partial O (bf16) + l (fp32)
    flash_mfma<<<1024, 256, 0, stream>>>(qkv_bf, vt_bf, po, lp);
    // combine splits -> attn bf16 [4096,1024]
    reduce_o<<<4096, 256, 0, stream>>>(po, lp, attn_bf);
    // y = attn @ w_out^T + b_out -> fp32
    gemm_bf16<INNERR, false, true, false><<<dim3(16, 32), 256, 0, stream>>>(
        attn_bf, wout_bf, b_out, nullptr, nullptr, y, INNERR);
}